// Round 11
// baseline (304.313 us; speedup 1.0000x reference)
//
#include <hip/hip_runtime.h>

typedef float v4f __attribute__((ext_vector_type(4)));

#define NB   32     // batch
#define NT   8      // timesteps
#define NC   128    // channels
#define NQ   256    // float4s per (H*W)=1024 plane
#define CRED 32     // C/red
#define PADI 32     // ints of padding per arrival counter (128 B line)

// R10 lesson: wave-0's own x prefetch shares its vmcnt queue with the
// means-fetch -> the per-step chain drains the machine-wide 16.8 MB prefetch
// burst (vmcnt(0) before means use). Fix: wave 1 stages wave-0's next-x
// through LDS; wave 0's vmcnt holds only publish stores / means loads.
// R9 lesson: all g_xsum consumption confined to the spinning wave (wave 0) +
// compiler memory barrier. R8: parallel coalesced LLC fetch. R7: park
// threads, single-lane poller, block-lockstep streaming. R6: big spike
// stores live in a separate, sync-free kernel (K2, ~29 us).
__device__ int                g_arrive[NB * PADI];      // per-batch arrival counters
__device__ unsigned long long g_xsum[2 * NB * NC];      // double-buffered mean bits
__device__ float              g_tau[NB * NT];           // [b][t]; t>=1 written by K1

__global__ __launch_bounds__(256)
void lif_init() {
    int i = threadIdx.x + blockIdx.x * blockDim.x;
    if (i < NB * PADI) g_arrive[i] = 0;
}

// ---------------------------------------------------------------------------
// K1: tau solver. 1024 blocks (block = (b, 4-channel group)), mem in
// registers, no spike stores. Per step: fma/reduce -> wave-0 publishes means
// + arrives -> waves 1-3 self-prefetch next x; wave 1 also stages wave-0's
// next-x slice into LDS -> wave-0 lane-0 spins -> wave-0 fetches 128 means
// (clean vmcnt) -> LDS -> wave-0 MLP -> s_tau -> barrier -> next step.
// ---------------------------------------------------------------------------
__global__ __launch_bounds__(256, 4)
void lif_tau(const float* __restrict__ x,
             const float* __restrict__ w1,
             const float* __restrict__ b1,
             const float* __restrict__ w2,
             const float* __restrict__ b2)
{
    const int bid = blockIdx.x;          // 0..1023
    const int b   = bid >> 5;            // batch
    const int c0  = (bid & 31) << 2;     // first of 4 channels
    const int tid = threadIdx.x;
    const int wv  = tid >> 6;
    const int ln  = tid & 63;

    __shared__ double s_part[4][4];
    __shared__ double s_mlp[NC];         // staged means for this batch
    __shared__ v4f    s_xstage[4][64];   // wave-0's next-x slice (4 KB)
    __shared__ float  s_tau;

    const v4f* __restrict__ x4 = (const v4f*)x;

    v4f mem[4];
    #pragma unroll
    for (int p = 0; p < 4; ++p) mem[p] = (v4f){0.f, 0.f, 0.f, 0.f};

    float tau = 0.5f;                    // TAU0

    v4f xv[4];
    #pragma unroll
    for (int p = 0; p < 4; ++p)
        xv[p] = x4[((b * NT + 0) * NC + c0 + p) * NQ + tid];  // prologue (all waves)

    for (int t = 0; t < NT - 1; ++t) {   // t = 0..6, produces g_tau[b][1..7]
        // wave 0, t>=1: pick up its x slice from LDS (staged by wave 1 at t-1;
        // ordered by barrier B of t-1 / barrier A of t)
        if (wv == 0 && t > 0) {
            #pragma unroll
            for (int p = 0; p < 4; ++p) xv[p] = s_xstage[p][ln];
        }

        double psum[4];
        #pragma unroll
        for (int p = 0; p < 4; ++p) {
            v4f m = mem[p];
            m.x = fmaf(m.x, tau, xv[p].x);
            m.y = fmaf(m.y, tau, xv[p].y);
            m.z = fmaf(m.z, tau, xv[p].z);
            m.w = fmaf(m.w, tau, xv[p].w);
            psum[p] = ((double)m.x + (double)m.y) + ((double)m.z + (double)m.w);
            m.x = (m.x > 1.0f) ? 0.0f : m.x;     // reset; spikes written by K2
            m.y = (m.y > 1.0f) ? 0.0f : m.y;
            m.z = (m.z > 1.0f) ? 0.0f : m.z;
            m.w = (m.w > 1.0f) ? 0.0f : m.w;
            mem[p] = m;
        }

        #pragma unroll
        for (int p = 0; p < 4; ++p) {
            double s = psum[p];
            #pragma unroll
            for (int off = 32; off > 0; off >>= 1) s += __shfl_down(s, off);
            if (ln == 0) s_part[p][wv] = s;
        }
        __syncthreads();                 // barrier A: s_part ready

        if (wv == 0) {
            if (ln < 4) {                // combine 4 waves, publish 4 means
                double s = (s_part[ln][0] + s_part[ln][1]) +
                           (s_part[ln][2] + s_part[ln][3]);
                __hip_atomic_store(&g_xsum[(t & 1) * (NB * NC) + b * NC + c0 + ln],
                                   __double_as_longlong(s * (1.0 / 1024.0)),
                                   __ATOMIC_RELAXED, __HIP_MEMORY_SCOPE_AGENT);
            }
            __builtin_amdgcn_s_waitcnt(0);   // publish committed (only these stores)
            if (ln == 0)
                __hip_atomic_fetch_add(&g_arrive[b * PADI], 1,
                                       __ATOMIC_RELAXED, __HIP_MEMORY_SCOPE_AGENT);
        }

        // waves 1-3: self-prefetch next x (overlaps spin; drains while parked
        // at barrier B). Wave 1 additionally stages wave-0's slice into LDS so
        // wave-0's vmcnt queue stays clean for the means fetch.
        if (t + 1 < NT - 1) {
            if (wv >= 1) {
                #pragma unroll
                for (int p = 0; p < 4; ++p)
                    xv[p] = x4[((b * NT + (t + 1)) * NC + c0 + p) * NQ + tid];
            }
            if (wv == 1) {
                #pragma unroll
                for (int p = 0; p < 4; ++p)
                    s_xstage[p][ln] =
                        x4[((b * NT + (t + 1)) * NC + c0 + p) * NQ + ln];
            }
        }

        if (wv == 0) {
            // lane-0 spin; whole wave rides the loop -> control-flow ordering
            if (ln == 0) {
                const int target = 32 * (t + 1);  // monotonic; zeroed by lif_init
                while (__hip_atomic_load(&g_arrive[b * PADI],
                                         __ATOMIC_RELAXED,
                                         __HIP_MEMORY_SCOPE_AGENT) < target)
                    __builtin_amdgcn_s_sleep(1);
            }
            asm volatile("" ::: "memory");   // no compiler hoist above the spin

            // parallel coalesced fetch: 64 lanes x 2 means -> LDS
            // (wave-0 has no other vmem outstanding -> wait is means-only)
            {
                const unsigned long long* __restrict__ xm =
                    g_xsum + (t & 1) * (NB * NC) + b * NC;
                unsigned long long u0 = __hip_atomic_load(
                    &xm[ln], __ATOMIC_RELAXED, __HIP_MEMORY_SCOPE_AGENT);
                unsigned long long u1 = __hip_atomic_load(
                    &xm[ln + 64], __ATOMIC_RELAXED, __HIP_MEMORY_SCOPE_AGENT);
                s_mlp[ln]      = __longlong_as_double(u0);
                s_mlp[ln + 64] = __longlong_as_double(u1);
            }

            // MLP (128->32->1) on wave 0, bit-identical summation order
            double e = 0.0;
            if (ln < CRED) {
                const float* __restrict__ w1r = w1 + ln * NC;
                double acc = (double)b1[ln];
                #pragma unroll 8
                for (int cc = 0; cc < NC; ++cc)
                    acc += s_mlp[cc] * (double)w1r[cc];
                double emb = acc > 0.0 ? acc : 0.0;
                e = emb * (double)w2[ln];
            }
            #pragma unroll
            for (int off = 32; off > 0; off >>= 1) e += __shfl_down(e, off);
            if (ln == 0) {
                double z = e + (double)b2[0];
                float nt_tau = (float)(1.0 / (1.0 + exp(-z)));
                s_tau = nt_tau;
                if ((bid & 31) == 0)                 // one writer per batch
                    g_tau[b * NT + t + 1] = nt_tau;  // flushed at kernel end
            }
        }
        __syncthreads();                 // barrier B: s_tau ready
        tau = s_tau;
    }
}

// ---------------------------------------------------------------------------
// K2: spike writer. Taus known -> ZERO synchronization. One block per (b,c)
// plane (4096 blocks); each thread recomputes its element's mem trajectory
// across all 8 steps with bit-identical arithmetic and streams spikes.
// Measured ~29 us (R8) — near the 135 MB write floor.
// ---------------------------------------------------------------------------
__global__ __launch_bounds__(256)
void lif_spike(const float* __restrict__ x, float* __restrict__ out)
{
    const int bid = blockIdx.x;          // 0..4095
    const int b   = bid >> 7;            // batch
    const int c   = bid & 127;           // channel
    const int tid = threadIdx.x;         // float4 index within plane

    const v4f* __restrict__ x4 = (const v4f*)x;
    v4f* __restrict__ o4       = (v4f*)out;

    float taus[NT];
    taus[0] = 0.5f;
    #pragma unroll
    for (int t = 1; t < NT; ++t) taus[t] = g_tau[b * NT + t];

    v4f m = (v4f){0.f, 0.f, 0.f, 0.f};
    #pragma unroll
    for (int t = 0; t < NT; ++t) {
        const long idx = ((long)(b * NT + t) * NC + c) * NQ + tid;
        v4f xv = x4[idx];                // L3-warm from K1
        m.x = fmaf(m.x, taus[t], xv.x);
        m.y = fmaf(m.y, taus[t], xv.y);
        m.z = fmaf(m.z, taus[t], xv.z);
        m.w = fmaf(m.w, taus[t], xv.w);
        v4f sp;
        sp.x = (m.x > 1.0f) ? 1.0f : 0.0f;   // zif(mem-1): exact (Sterbenz)
        sp.y = (m.y > 1.0f) ? 1.0f : 0.0f;
        sp.z = (m.z > 1.0f) ? 1.0f : 0.0f;
        sp.w = (m.w > 1.0f) ? 1.0f : 0.0f;
        __builtin_nontemporal_store(sp, o4 + idx);
        m.x = (m.x > 1.0f) ? 0.0f : m.x;     // (1-spike)*mem
        m.y = (m.y > 1.0f) ? 0.0f : m.y;
        m.z = (m.z > 1.0f) ? 0.0f : m.z;
        m.w = (m.w > 1.0f) ? 0.0f : m.w;
    }
}

extern "C" void kernel_launch(void* const* d_in, const int* in_sizes, int n_in,
                              void* d_out, int out_size, void* d_ws, size_t ws_size,
                              hipStream_t stream) {
    const float* x  = (const float*)d_in[0];
    const float* w1 = (const float*)d_in[1];
    const float* b1 = (const float*)d_in[2];
    const float* w2 = (const float*)d_in[3];
    const float* b2 = (const float*)d_in[4];
    float* out      = (float*)d_out;

    hipLaunchKernelGGL(lif_init, dim3((NB * PADI + 255) / 256), dim3(256),
                       0, stream);
    hipLaunchKernelGGL(lif_tau, dim3(NB * NC / 4), dim3(256), 0, stream,
                       x, w1, b1, w2, b2);
    hipLaunchKernelGGL(lif_spike, dim3(NB * NC), dim3(256), 0, stream,
                       x, out);
}